// Round 8
// baseline (623.964 us; speedup 1.0000x reference)
//
#include <hip/hip_runtime.h>
#include <math.h>

// FeatureWeightNet: grid_sample(bilinear,border) -> group correlation (G=8) ->
// MLP(8->16->8->1) with per-batch BN stats -> sigmoid.
// R15 = R12 (best, 245.3us) with stats1 FUSED into k_sample:
//  - lane j accumulates P[j][m] = sum s_j * s_{j xor m} (7 shfl_xor + 8 FMA
//    per neighbor) + sum s_j; cross-pixel butterfly (xor 8/16/32) + LDS
//    -> 72 floats/block. M[j][k] = P[j][j^k] reconstructed in reduce1's
//    quadratic form (only w^T M w is ever needed).
//  - partials live in d_out[0..5120*72) (featB is LIVE during sample; out is
//    dead until k_final overwrites it).
//  - removes the stats1 dispatch (~8us kernel + ~10us launch gap) and one
//    full 23.6 MB pass over sB.
//  - stats2 / reduce2 / final byte-identical to R12 (straight-line 4px =
//    LICM-proof; R8-R10 spill disease). No atomics, no fences (R13 lesson).
// 6 dispatches.

constexpr int   Bc  = 2;
constexpr int   Cc  = 64;
constexpr int   Hc  = 256;
constexpr int   Wc  = 320;
constexpr int   NBc = 9;
constexpr int   HWc = Hc * Wc;            // 81920
constexpr int   NPIX = Bc * HWc;          // 163840
constexpr int   NPT  = Bc * NBc * HWc;    // 1474560 (= out_size)
constexpr float EPSV = 1e-5f;

constexpr int NBLK_S = NPIX / 32;         // 5120 sample blocks
constexpr int NBT4   = NPT / 1024;        // 1440 tail blocks (4 px/thread)

// workspace layout in float units.  featB (21 MB) + sB (23.6 MB).
constexpr size_t OFF_FEATB = 0;                               // NHWC bf16: NPIX*64 ushort
constexpr size_t OFF_SB    = OFF_FEATB + (size_t)NPIX * 32;   // s bf16: NPT*8 ushort
// scratch overlays featB (dead after k_sample):
constexpr size_t OFF_P2    = 0;                                // NBT4*16 floats
constexpr size_t OFF_PAR1  = OFF_P2 + (size_t)NBT4 * 16;       // 272 floats
constexpr size_t OFF_PAR2  = OFF_PAR1 + 272;                   // 33 floats

__device__ __forceinline__ unsigned short f2bf_rne(float v) {
  unsigned int u = __float_as_uint(v);
  unsigned int r = (u + 0x7fffu + ((u >> 16) & 1u)) >> 16;
  return (unsigned short)r;
}
__device__ __forceinline__ void unpack8(uint4 u, float f[8]) {
  f[0] = __uint_as_float(u.x << 16);
  f[1] = __uint_as_float(u.x & 0xffff0000u);
  f[2] = __uint_as_float(u.y << 16);
  f[3] = __uint_as_float(u.y & 0xffff0000u);
  f[4] = __uint_as_float(u.z << 16);
  f[5] = __uint_as_float(u.z & 0xffff0000u);
  f[6] = __uint_as_float(u.w << 16);
  f[7] = __uint_as_float(u.w & 0xffff0000u);
}
__device__ __forceinline__ float dot8(const float s[8], float4 wa, float4 wb) {
  return s[0] * wa.x + s[1] * wa.y + s[2] * wa.z + s[3] * wa.w +
         s[4] * wb.x + s[5] * wb.y + s[6] * wb.z + s[7] * wb.w;
}

// ---------------------------------------------------------------------------
// K0: NCHW fp32 -> NHWC bf16 transpose.
__global__ __launch_bounds__(256) void k_transpose(
    const float* __restrict__ feat, unsigned short* __restrict__ featB) {
  __shared__ float lds[64][65];
  const int tid  = threadIdx.x;
  const int b    = blockIdx.x / (HWc / 64);
  const int tile = blockIdx.x % (HWc / 64);
  const int hw0  = tile * 64;
  const int p    = tid & 63;
  const int ty   = tid >> 6;  // 0..3

  const float* src = feat + (size_t)b * Cc * HWc + hw0 + p;
#pragma unroll
  for (int c0 = 0; c0 < 64; c0 += 4) {
    lds[c0 + ty][p] = src[(size_t)(c0 + ty) * HWc];
  }
  __syncthreads();
  const int ch = tid & 63;
  unsigned short* dst = featB + ((size_t)b * HWc + hw0) * 64 + ch;
#pragma unroll
  for (int p0 = 0; p0 < 64; p0 += 4) {
    dst[(size_t)(p0 + ty) * 64] = f2bf_rne(lds[ch][p0 + ty]);
  }
}

// ---------------------------------------------------------------------------
// K1: grid sample + group correlation + FUSED s-moment partials.
// Gather structure identical to the proven 3.9 TB/s kernel; adds per-neighbor
// 7 shfl_xor + 8 FMA + 1 add, and a ~75-instruction epilogue.
__global__ __launch_bounds__(256) void k_sample(
    const float* __restrict__ grid, const unsigned short* __restrict__ featB,
    unsigned short* __restrict__ sOut, float* __restrict__ partM) {
  const int tid = threadIdx.x;
  const int cid = blockIdx.x * 32 + (tid >> 3);  // pixel id in [0, NPIX)
  const int j   = tid & 7;                       // group
  const int b   = cid / HWc;
  const int hw  = cid - b * HWc;
  const int h   = hw / Wc;
  const int w   = hw - h * Wc;

  const uint4* fbAll = (const uint4*)featB;
  const uint4 ur = fbAll[(size_t)cid * 8 + j];
  float r[8];
  unpack8(ur, r);

  const uint4* fb = fbAll + (size_t)b * HWc * 8;

  float macc[8];
#pragma unroll
  for (int m = 0; m < 8; ++m) macc[m] = 0.f;
  float msum = 0.f;

#pragma unroll 3
  for (int n = 0; n < NBc; ++n) {
    const size_t gi = ((((size_t)b * NBc + n) * Hc + h) * Wc + w) * 2;
    const float2 g2 = *(const float2*)(grid + gi);
    float ix = ((g2.x + 1.f) * (float)Wc - 1.f) * 0.5f;
    float iy = ((g2.y + 1.f) * (float)Hc - 1.f) * 0.5f;
    ix = fminf(fmaxf(ix, 0.f), (float)(Wc - 1));
    iy = fminf(fmaxf(iy, 0.f), (float)(Hc - 1));
    const float x0f = floorf(ix), y0f = floorf(iy);
    const float fx = ix - x0f, fy = iy - y0f;
    const int x0 = (int)x0f, y0 = (int)y0f;
    const int x1 = min(x0 + 1, Wc - 1), y1 = min(y0 + 1, Hc - 1);
    const float w00 = (1.f - fx) * (1.f - fy);
    const float w01 = fx * (1.f - fy);
    const float w10 = (1.f - fx) * fy;
    const float w11 = fx * fy;

    const uint4 u00 = fb[(size_t)(y0 * Wc + x0) * 8 + j];
    const uint4 u01 = fb[(size_t)(y0 * Wc + x1) * 8 + j];
    const uint4 u10 = fb[(size_t)(y1 * Wc + x0) * 8 + j];
    const uint4 u11 = fb[(size_t)(y1 * Wc + x1) * 8 + j];
    float a[8], c[8], d[8], e[8];
    unpack8(u00, a);
    unpack8(u01, c);
    unpack8(u10, d);
    unpack8(u11, e);

    float s = 0.f;
#pragma unroll
    for (int k = 0; k < 8; ++k) {
      s += (w00 * a[k] + w01 * c[k] + w10 * d[k] + w11 * e[k]) * r[k];
    }
    s *= 0.125f;  // mean over C/G = 8

    const size_t pt = ((size_t)b * NBc + n) * HWc + hw;
    sOut[pt * 8 + j] = f2bf_rne(s);

    // fused moments: lanes j..j^7 are the 8 groups of THIS pixel (xor<8
    // stays within the 8-lane cluster).
    macc[0] += s * s;
#pragma unroll
    for (int m = 1; m < 8; ++m) macc[m] += s * __shfl_xor(s, m);
    msum += s;
  }

  // cross-pixel reduce: lanes differing in bits 3..5 hold other pixels.
#pragma unroll
  for (int m = 0; m < 8; ++m) {
    macc[m] += __shfl_xor(macc[m], 8);
    macc[m] += __shfl_xor(macc[m], 16);
    macc[m] += __shfl_xor(macc[m], 32);
  }
  msum += __shfl_xor(msum, 8);
  msum += __shfl_xor(msum, 16);
  msum += __shfl_xor(msum, 32);

  __shared__ float mred[4][72];
  const int lane = tid & 63, wid = tid >> 6;
  if (lane < 8) {
#pragma unroll
    for (int m = 0; m < 8; ++m) mred[wid][lane * 9 + m] = macc[m];
    mred[wid][lane * 9 + 8] = msum;
  }
  __syncthreads();
  if (tid < 72) {
    partM[(size_t)blockIdx.x * 72 + tid] =
        mred[0][tid] + mred[1][tid] + mred[2][tid] + mred[3][tid];
  }
}

// ---------------------------------------------------------------------------
// K2: reduce1 (1 block) — partM (5120 x 72) -> moments -> bn1; write folded
// params: par1[0..127]=w0p (a1-folded w0), [128..143]=c1v, [144..271]=w1t.
// M[j][k] = tot[j*9 + (j^k)]; S[j] = tot[j*9+8].
__global__ __launch_bounds__(256) void k_reduce1(
    const float* __restrict__ partM, const float* __restrict__ w0,
    const float* __restrict__ w1, const float* __restrict__ g0,
    const float* __restrict__ b0, float* __restrict__ par1) {
  __shared__ float st[216], tot[72], a1s[16];
  const int tid = threadIdx.x;
  if (tid < 216) {
    const int c = tid % 72, chk = tid / 72;  // 3 row-chunks x 72 cols
    float a = 0.f;
    for (int r = chk; r < NBLK_S; r += 3) a += partM[(size_t)r * 72 + c];
    st[tid] = a;
  }
  __syncthreads();
  if (tid < 72) tot[tid] = st[tid] + st[72 + tid] + st[144 + tid];
  __syncthreads();
  if (tid < 16) {
    float wr[8];
    float mean = 0.f, ey2 = 0.f;
#pragma unroll
    for (int jj = 0; jj < 8; ++jj) {
      wr[jj] = w0[tid * 8 + jj];
      mean += wr[jj] * tot[jj * 9 + 8];
    }
#pragma unroll
    for (int jj = 0; jj < 8; ++jj) {
#pragma unroll
      for (int kk = 0; kk < 8; ++kk) {
        ey2 += wr[jj] * wr[kk] * tot[jj * 9 + (jj ^ kk)];
      }
    }
    const float invN = 1.f / (float)NPT;
    mean *= invN;
    ey2 *= invN;
    const float var = ey2 - mean * mean;
    const float a = g0[tid] * rsqrtf(var + EPSV);
    a1s[tid] = a;
    par1[128 + tid] = b0[tid] - mean * a;
  }
  __syncthreads();
  if (tid < 128) {
    par1[tid] = a1s[tid >> 3] * w0[tid];                 // w0p
    par1[144 + (tid & 15) * 8 + (tid >> 4)] = w1[tid];   // w1t
  }
}

// ---------------------------------------------------------------------------
// K3: stats2 — straight-line 4 px/thread (LICM-proof); z/z^2 partials.
// Byte-identical to R12.
__global__ __launch_bounds__(256) void k_stats2(
    const unsigned short* __restrict__ sB, const float* __restrict__ par1,
    float* __restrict__ part2) {
  __shared__ float w0ps[128], c1vs[16], w1ts[128];
  __shared__ float red[64];
  const int tid = threadIdx.x;
  if (tid < 128) {
    w0ps[tid] = par1[tid];
    w1ts[tid] = par1[144 + tid];
  }
  if (tid >= 128 && tid < 144) c1vs[tid - 128] = par1[tid];
  __syncthreads();

  const uint4* src = (const uint4*)sB + (size_t)blockIdx.x * 1024 + tid;
  float s0[8], s1[8], s2[8], s3[8];
  unpack8(src[0], s0);
  unpack8(src[256], s1);
  unpack8(src[512], s2);
  unpack8(src[768], s3);

  float z0[8], z1[8], z2[8], z3[8];
#pragma unroll
  for (int o = 0; o < 8; ++o) { z0[o] = 0.f; z1[o] = 0.f; z2[o] = 0.f; z3[o] = 0.f; }
#pragma unroll
  for (int c = 0; c < 16; ++c) {
    const float4 wa = *(const float4*)(w0ps + c * 8);
    const float4 wb = *(const float4*)(w0ps + c * 8 + 4);
    const float cc = c1vs[c];
    const float4 ta = *(const float4*)(w1ts + c * 8);
    const float4 tb = *(const float4*)(w1ts + c * 8 + 4);
    const float xa = fmaxf(dot8(s0, wa, wb) + cc, 0.f);
    const float xb = fmaxf(dot8(s1, wa, wb) + cc, 0.f);
    const float xc = fmaxf(dot8(s2, wa, wb) + cc, 0.f);
    const float xd = fmaxf(dot8(s3, wa, wb) + cc, 0.f);
    z0[0] += ta.x * xa; z0[1] += ta.y * xa; z0[2] += ta.z * xa; z0[3] += ta.w * xa;
    z0[4] += tb.x * xa; z0[5] += tb.y * xa; z0[6] += tb.z * xa; z0[7] += tb.w * xa;
    z1[0] += ta.x * xb; z1[1] += ta.y * xb; z1[2] += ta.z * xb; z1[3] += ta.w * xb;
    z1[4] += tb.x * xb; z1[5] += tb.y * xb; z1[6] += tb.z * xb; z1[7] += tb.w * xb;
    z2[0] += ta.x * xc; z2[1] += ta.y * xc; z2[2] += ta.z * xc; z2[3] += ta.w * xc;
    z2[4] += tb.x * xc; z2[5] += tb.y * xc; z2[6] += tb.z * xc; z2[7] += tb.w * xc;
    z3[0] += ta.x * xd; z3[1] += ta.y * xd; z3[2] += ta.z * xd; z3[3] += ta.w * xd;
    z3[4] += tb.x * xd; z3[5] += tb.y * xd; z3[6] += tb.z * xd; z3[7] += tb.w * xd;
  }

  const int wid = tid >> 6;
#pragma unroll
  for (int o = 0; o < 8; ++o) {
    float v = (z0[o] + z1[o]) + (z2[o] + z3[o]);
    float v2 = (z0[o] * z0[o] + z1[o] * z1[o]) + (z2[o] * z2[o] + z3[o] * z3[o]);
#pragma unroll
    for (int off = 32; off; off >>= 1) {
      v += __shfl_xor(v, off);
      v2 += __shfl_xor(v2, off);
    }
    if ((tid & 63) == 0) {
      red[wid * 16 + o] = v;
      red[wid * 16 + 8 + o] = v2;
    }
  }
  __syncthreads();
  if (tid < 16) {
    part2[blockIdx.x * 16 + tid] =
        red[tid] + red[16 + tid] + red[32 + tid] + red[48 + tid];
  }
}

// ---------------------------------------------------------------------------
// K3b: reduce2 (1 block) — part2 (1440 x 16) -> bn2; par2[o*4+{0,1,2}] =
// {a2,c2,ws}, par2[32] = bs.
__global__ __launch_bounds__(256) void k_reduce2(
    const float* __restrict__ part2, const float* __restrict__ g1,
    const float* __restrict__ b1, const float* __restrict__ wsW,
    const float* __restrict__ bs, float* __restrict__ par2) {
  __shared__ float red[1024], totz[16];
  const int tid = threadIdx.x;
  {  // float4 partial reads: 64 row-chunks x 4 col-quads
    const int cq = tid & 3, chk = tid >> 2;
    float4 a = make_float4(0.f, 0.f, 0.f, 0.f);
    for (int r = chk; r < NBT4; r += 64) {
      const float4 v = *(const float4*)(part2 + r * 16 + cq * 4);
      a.x += v.x; a.y += v.y; a.z += v.z; a.w += v.w;
    }
    red[chk * 16 + cq * 4 + 0] = a.x;
    red[chk * 16 + cq * 4 + 1] = a.y;
    red[chk * 16 + cq * 4 + 2] = a.z;
    red[chk * 16 + cq * 4 + 3] = a.w;
  }
  __syncthreads();
  if (tid < 16) {
    float v = 0.f;
#pragma unroll
    for (int k = 0; k < 64; ++k) v += red[k * 16 + tid];
    totz[tid] = v;
  }
  __syncthreads();
  if (tid < 8) {
    const float invN = 1.f / (float)NPT;
    const float mean = totz[tid] * invN;
    const float var = totz[8 + tid] * invN - mean * mean;
    const float a = g1[tid] * rsqrtf(var + EPSV);
    par2[tid * 4 + 0] = a;
    par2[tid * 4 + 1] = b1[tid] - mean * a;
    par2[tid * 4 + 2] = wsW[tid];
    par2[tid * 4 + 3] = 0.f;
  }
  if (tid == 8) par2[32] = bs[0];
}

// ---------------------------------------------------------------------------
// K4: final — straight-line 4 px/thread, full MLP + sigmoid -> out.
// (Overwrites the partM region at the head of out.)
__global__ __launch_bounds__(256) void k_final(
    const unsigned short* __restrict__ sB, const float* __restrict__ par1,
    const float* __restrict__ par2, float* __restrict__ out) {
  __shared__ float w0ps[128], c1vs[16], w1ts[128], w2s[33];
  const int tid = threadIdx.x;
  if (tid < 128) {
    w0ps[tid] = par1[tid];
    w1ts[tid] = par1[144 + tid];
  }
  if (tid >= 128 && tid < 144) c1vs[tid - 128] = par1[tid];
  if (tid >= 160 && tid < 193) w2s[tid - 160] = par2[tid - 160];
  __syncthreads();

  const uint4* src = (const uint4*)sB + (size_t)blockIdx.x * 1024 + tid;
  float s0[8], s1[8], s2[8], s3[8];
  unpack8(src[0], s0);
  unpack8(src[256], s1);
  unpack8(src[512], s2);
  unpack8(src[768], s3);

  float z0[8], z1[8], z2[8], z3[8];
#pragma unroll
  for (int o = 0; o < 8; ++o) { z0[o] = 0.f; z1[o] = 0.f; z2[o] = 0.f; z3[o] = 0.f; }
#pragma unroll
  for (int c = 0; c < 16; ++c) {
    const float4 wa = *(const float4*)(w0ps + c * 8);
    const float4 wb = *(const float4*)(w0ps + c * 8 + 4);
    const float cc = c1vs[c];
    const float4 ta = *(const float4*)(w1ts + c * 8);
    const float4 tb = *(const float4*)(w1ts + c * 8 + 4);
    const float xa = fmaxf(dot8(s0, wa, wb) + cc, 0.f);
    const float xb = fmaxf(dot8(s1, wa, wb) + cc, 0.f);
    const float xc = fmaxf(dot8(s2, wa, wb) + cc, 0.f);
    const float xd = fmaxf(dot8(s3, wa, wb) + cc, 0.f);
    z0[0] += ta.x * xa; z0[1] += ta.y * xa; z0[2] += ta.z * xa; z0[3] += ta.w * xa;
    z0[4] += tb.x * xa; z0[5] += tb.y * xa; z0[6] += tb.z * xa; z0[7] += tb.w * xa;
    z1[0] += ta.x * xb; z1[1] += ta.y * xb; z1[2] += ta.z * xb; z1[3] += ta.w * xb;
    z1[4] += tb.x * xb; z1[5] += tb.y * xb; z1[6] += tb.z * xb; z1[7] += tb.w * xb;
    z2[0] += ta.x * xc; z2[1] += ta.y * xc; z2[2] += ta.z * xc; z2[3] += ta.w * xc;
    z2[4] += tb.x * xc; z2[5] += tb.y * xc; z2[6] += tb.z * xc; z2[7] += tb.w * xc;
    z3[0] += ta.x * xd; z3[1] += ta.y * xd; z3[2] += ta.z * xd; z3[3] += ta.w * xd;
    z3[4] += tb.x * xd; z3[5] += tb.y * xd; z3[6] += tb.z * xd; z3[7] += tb.w * xd;
  }

  const float bsr = w2s[32];
  float r0 = bsr, r1 = bsr, r2 = bsr, r3 = bsr;
#pragma unroll
  for (int o = 0; o < 8; ++o) {
    const float4 pr = *(const float4*)(w2s + o * 4);
    r0 += pr.z * fmaxf(fmaf(pr.x, z0[o], pr.y), 0.f);
    r1 += pr.z * fmaxf(fmaf(pr.x, z1[o], pr.y), 0.f);
    r2 += pr.z * fmaxf(fmaf(pr.x, z2[o], pr.y), 0.f);
    r3 += pr.z * fmaxf(fmaf(pr.x, z3[o], pr.y), 0.f);
  }
  float* op = out + (size_t)blockIdx.x * 1024 + tid;
  op[0]   = 1.f / (1.f + __expf(-r0));
  op[256] = 1.f / (1.f + __expf(-r1));
  op[512] = 1.f / (1.f + __expf(-r2));
  op[768] = 1.f / (1.f + __expf(-r3));
}

// ---------------------------------------------------------------------------
extern "C" void kernel_launch(void* const* d_in, const int* in_sizes, int n_in,
                              void* d_out, int out_size, void* d_ws,
                              size_t ws_size, hipStream_t stream) {
  const float* feat = (const float*)d_in[0];  // [2,64,256,320]
  const float* grid = (const float*)d_in[1];  // [2,2304,320,2]
  const float* w0 = (const float*)d_in[2];    // [16,8]
  const float* g0 = (const float*)d_in[3];
  const float* b0 = (const float*)d_in[4];
  const float* w1 = (const float*)d_in[5];    // [8,16]
  const float* g1 = (const float*)d_in[6];
  const float* b1 = (const float*)d_in[7];
  const float* wsW = (const float*)d_in[8];   // [1,8]
  const float* bs = (const float*)d_in[9];    // [1]
  float* out = (float*)d_out;

  float* wsf = (float*)d_ws;
  unsigned short* featB = (unsigned short*)(wsf + OFF_FEATB);
  unsigned short* sB    = (unsigned short*)(wsf + OFF_SB);
  float* part2 = wsf + OFF_P2;   // overlays featB (dead after k_sample)
  float* par1  = wsf + OFF_PAR1;
  float* par2  = wsf + OFF_PAR2;
  float* partM = out;            // 5120*72 floats; k_final overwrites

  k_transpose<<<Bc * (HWc / 64), 256, 0, stream>>>(feat, featB);
  k_sample<<<NBLK_S, 256, 0, stream>>>(grid, featB, sB, partM);
  k_reduce1<<<1, 256, 0, stream>>>(partM, w0, w1, g0, b0, par1);
  k_stats2<<<NBT4, 256, 0, stream>>>(sB, par1, part2);
  k_reduce2<<<1, 256, 0, stream>>>(part2, g1, b1, wsW, bs, par2);
  k_final<<<NBT4, 256, 0, stream>>>(sB, par1, par2, out);
}

// Round 9
// 273.436 us; speedup vs baseline: 2.2819x; 2.2819x over previous
//
#include <hip/hip_runtime.h>
#include <math.h>

// FeatureWeightNet: grid_sample(bilinear,border) -> group correlation (G=8) ->
// MLP(8->16->8->1) with per-batch BN stats -> sigmoid.
// R16 = R15 (stats1 fused into k_sample) with the reduce kernels rebuilt for
// ILP. R15's reduce1 was a 1707-iteration scalar dependent load->add chain in
// ONE block = 408-420us (measured). Law from R12/R14/R15: single-block reduce
// cost ~= chain_length x mem latency. Fix: vector loads + MANY independent
// accumulators.
//  - reduce1: 18 float4-cols x 14 row-chunks, 8 independent float4 accums
//    per thread (chain 1707 -> ~45), 14-way LDS fold. ~15us.
//  - reduce2: 4 independent float4 accums (chain 23 -> ~6).
//  - everything else byte-identical to R15 (sample+fused moments ~85us,
//    straight-line LICM-proof tails, no atomics, no fences). 6 dispatches.

constexpr int   Bc  = 2;
constexpr int   Cc  = 64;
constexpr int   Hc  = 256;
constexpr int   Wc  = 320;
constexpr int   NBc = 9;
constexpr int   HWc = Hc * Wc;            // 81920
constexpr int   NPIX = Bc * HWc;          // 163840
constexpr int   NPT  = Bc * NBc * HWc;    // 1474560 (= out_size)
constexpr float EPSV = 1e-5f;

constexpr int NBLK_S = NPIX / 32;         // 5120 sample blocks
constexpr int NBT4   = NPT / 1024;        // 1440 tail blocks (4 px/thread)

// workspace layout in float units.  featB (21 MB) + sB (23.6 MB).
constexpr size_t OFF_FEATB = 0;                               // NHWC bf16: NPIX*64 ushort
constexpr size_t OFF_SB    = OFF_FEATB + (size_t)NPIX * 32;   // s bf16: NPT*8 ushort
// scratch overlays featB (dead after k_sample):
constexpr size_t OFF_P2    = 0;                                // NBT4*16 floats
constexpr size_t OFF_PAR1  = OFF_P2 + (size_t)NBT4 * 16;       // 272 floats
constexpr size_t OFF_PAR2  = OFF_PAR1 + 272;                   // 33 floats

__device__ __forceinline__ unsigned short f2bf_rne(float v) {
  unsigned int u = __float_as_uint(v);
  unsigned int r = (u + 0x7fffu + ((u >> 16) & 1u)) >> 16;
  return (unsigned short)r;
}
__device__ __forceinline__ void unpack8(uint4 u, float f[8]) {
  f[0] = __uint_as_float(u.x << 16);
  f[1] = __uint_as_float(u.x & 0xffff0000u);
  f[2] = __uint_as_float(u.y << 16);
  f[3] = __uint_as_float(u.y & 0xffff0000u);
  f[4] = __uint_as_float(u.z << 16);
  f[5] = __uint_as_float(u.z & 0xffff0000u);
  f[6] = __uint_as_float(u.w << 16);
  f[7] = __uint_as_float(u.w & 0xffff0000u);
}
__device__ __forceinline__ float dot8(const float s[8], float4 wa, float4 wb) {
  return s[0] * wa.x + s[1] * wa.y + s[2] * wa.z + s[3] * wa.w +
         s[4] * wb.x + s[5] * wb.y + s[6] * wb.z + s[7] * wb.w;
}
__device__ __forceinline__ void addf4(float4& a, const float4 v) {
  a.x += v.x; a.y += v.y; a.z += v.z; a.w += v.w;
}

// ---------------------------------------------------------------------------
// K0: NCHW fp32 -> NHWC bf16 transpose.
__global__ __launch_bounds__(256) void k_transpose(
    const float* __restrict__ feat, unsigned short* __restrict__ featB) {
  __shared__ float lds[64][65];
  const int tid  = threadIdx.x;
  const int b    = blockIdx.x / (HWc / 64);
  const int tile = blockIdx.x % (HWc / 64);
  const int hw0  = tile * 64;
  const int p    = tid & 63;
  const int ty   = tid >> 6;  // 0..3

  const float* src = feat + (size_t)b * Cc * HWc + hw0 + p;
#pragma unroll
  for (int c0 = 0; c0 < 64; c0 += 4) {
    lds[c0 + ty][p] = src[(size_t)(c0 + ty) * HWc];
  }
  __syncthreads();
  const int ch = tid & 63;
  unsigned short* dst = featB + ((size_t)b * HWc + hw0) * 64 + ch;
#pragma unroll
  for (int p0 = 0; p0 < 64; p0 += 4) {
    dst[(size_t)(p0 + ty) * 64] = f2bf_rne(lds[ch][p0 + ty]);
  }
}

// ---------------------------------------------------------------------------
// K1: grid sample + group correlation + FUSED s-moment partials.
// Gather structure identical to the proven 3.9 TB/s kernel.
__global__ __launch_bounds__(256) void k_sample(
    const float* __restrict__ grid, const unsigned short* __restrict__ featB,
    unsigned short* __restrict__ sOut, float* __restrict__ partM) {
  const int tid = threadIdx.x;
  const int cid = blockIdx.x * 32 + (tid >> 3);  // pixel id in [0, NPIX)
  const int j   = tid & 7;                       // group
  const int b   = cid / HWc;
  const int hw  = cid - b * HWc;
  const int h   = hw / Wc;
  const int w   = hw - h * Wc;

  const uint4* fbAll = (const uint4*)featB;
  const uint4 ur = fbAll[(size_t)cid * 8 + j];
  float r[8];
  unpack8(ur, r);

  const uint4* fb = fbAll + (size_t)b * HWc * 8;

  float macc[8];
#pragma unroll
  for (int m = 0; m < 8; ++m) macc[m] = 0.f;
  float msum = 0.f;

#pragma unroll 3
  for (int n = 0; n < NBc; ++n) {
    const size_t gi = ((((size_t)b * NBc + n) * Hc + h) * Wc + w) * 2;
    const float2 g2 = *(const float2*)(grid + gi);
    float ix = ((g2.x + 1.f) * (float)Wc - 1.f) * 0.5f;
    float iy = ((g2.y + 1.f) * (float)Hc - 1.f) * 0.5f;
    ix = fminf(fmaxf(ix, 0.f), (float)(Wc - 1));
    iy = fminf(fmaxf(iy, 0.f), (float)(Hc - 1));
    const float x0f = floorf(ix), y0f = floorf(iy);
    const float fx = ix - x0f, fy = iy - y0f;
    const int x0 = (int)x0f, y0 = (int)y0f;
    const int x1 = min(x0 + 1, Wc - 1), y1 = min(y0 + 1, Hc - 1);
    const float w00 = (1.f - fx) * (1.f - fy);
    const float w01 = fx * (1.f - fy);
    const float w10 = (1.f - fx) * fy;
    const float w11 = fx * fy;

    const uint4 u00 = fb[(size_t)(y0 * Wc + x0) * 8 + j];
    const uint4 u01 = fb[(size_t)(y0 * Wc + x1) * 8 + j];
    const uint4 u10 = fb[(size_t)(y1 * Wc + x0) * 8 + j];
    const uint4 u11 = fb[(size_t)(y1 * Wc + x1) * 8 + j];
    float a[8], c[8], d[8], e[8];
    unpack8(u00, a);
    unpack8(u01, c);
    unpack8(u10, d);
    unpack8(u11, e);

    float s = 0.f;
#pragma unroll
    for (int k = 0; k < 8; ++k) {
      s += (w00 * a[k] + w01 * c[k] + w10 * d[k] + w11 * e[k]) * r[k];
    }
    s *= 0.125f;  // mean over C/G = 8

    const size_t pt = ((size_t)b * NBc + n) * HWc + hw;
    sOut[pt * 8 + j] = f2bf_rne(s);

    // fused moments: lanes j..j^7 are the 8 groups of THIS pixel.
    macc[0] += s * s;
#pragma unroll
    for (int m = 1; m < 8; ++m) macc[m] += s * __shfl_xor(s, m);
    msum += s;
  }

  // cross-pixel reduce: lanes differing in bits 3..5 hold other pixels.
#pragma unroll
  for (int m = 0; m < 8; ++m) {
    macc[m] += __shfl_xor(macc[m], 8);
    macc[m] += __shfl_xor(macc[m], 16);
    macc[m] += __shfl_xor(macc[m], 32);
  }
  msum += __shfl_xor(msum, 8);
  msum += __shfl_xor(msum, 16);
  msum += __shfl_xor(msum, 32);

  __shared__ float mred[4][72];
  const int lane = tid & 63, wid = tid >> 6;
  if (lane < 8) {
#pragma unroll
    for (int m = 0; m < 8; ++m) mred[wid][lane * 9 + m] = macc[m];
    mred[wid][lane * 9 + 8] = msum;
  }
  __syncthreads();
  if (tid < 72) {
    partM[(size_t)blockIdx.x * 72 + tid] =
        mred[0][tid] + mred[1][tid] + mred[2][tid] + mred[3][tid];
  }
}

// ---------------------------------------------------------------------------
// K2: reduce1 (1 block) — partM (5120 x 72) -> moments -> bn1 -> folded
// params.  ILP summation: 18 float4-cols x 14 chunks, 8 independent float4
// accumulators per thread (8 loads in flight; chain ~45).
// M[j][k] = tot[j*9 + (j^k)]; S[j] = tot[j*9+8].
__global__ __launch_bounds__(256) void k_reduce1(
    const float* __restrict__ partM, const float* __restrict__ w0,
    const float* __restrict__ w1, const float* __restrict__ g0,
    const float* __restrict__ b0, float* __restrict__ par1) {
  __shared__ float st[14][72];
  __shared__ float tot[72], a1s[16];
  const int tid = threadIdx.x;
  if (tid < 252) {
    const int q = tid % 18;      // float4 column (18 x 4 = 72)
    const int chunk = tid / 18;  // 0..13
    const float4* base = (const float4*)partM;  // 18 float4 per row
    float4 a0 = make_float4(0.f, 0.f, 0.f, 0.f), a1 = a0, a2 = a0, a3 = a0,
           a4 = a0, a5 = a0, a6 = a0, a7 = a0;
    int r = chunk;
    while (r + 98 < NBLK_S) {  // 8 rows in flight per iteration
      addf4(a0, base[(size_t)(r)*18 + q]);
      addf4(a1, base[(size_t)(r + 14) * 18 + q]);
      addf4(a2, base[(size_t)(r + 28) * 18 + q]);
      addf4(a3, base[(size_t)(r + 42) * 18 + q]);
      addf4(a4, base[(size_t)(r + 56) * 18 + q]);
      addf4(a5, base[(size_t)(r + 70) * 18 + q]);
      addf4(a6, base[(size_t)(r + 84) * 18 + q]);
      addf4(a7, base[(size_t)(r + 98) * 18 + q]);
      r += 112;
    }
    for (; r < NBLK_S; r += 14) addf4(a0, base[(size_t)r * 18 + q]);
    addf4(a0, a1); addf4(a2, a3); addf4(a4, a5); addf4(a6, a7);
    addf4(a0, a2); addf4(a4, a6); addf4(a0, a4);
    st[chunk][q * 4 + 0] = a0.x;
    st[chunk][q * 4 + 1] = a0.y;
    st[chunk][q * 4 + 2] = a0.z;
    st[chunk][q * 4 + 3] = a0.w;
  }
  __syncthreads();
  if (tid < 72) {
    float v = 0.f;
#pragma unroll
    for (int c = 0; c < 14; ++c) v += st[c][tid];
    tot[tid] = v;
  }
  __syncthreads();
  if (tid < 16) {
    float wr[8];
    float mean = 0.f, ey2 = 0.f;
#pragma unroll
    for (int jj = 0; jj < 8; ++jj) {
      wr[jj] = w0[tid * 8 + jj];
      mean += wr[jj] * tot[jj * 9 + 8];
    }
#pragma unroll
    for (int jj = 0; jj < 8; ++jj) {
#pragma unroll
      for (int kk = 0; kk < 8; ++kk) {
        ey2 += wr[jj] * wr[kk] * tot[jj * 9 + (jj ^ kk)];
      }
    }
    const float invN = 1.f / (float)NPT;
    mean *= invN;
    ey2 *= invN;
    const float var = ey2 - mean * mean;
    const float a = g0[tid] * rsqrtf(var + EPSV);
    a1s[tid] = a;
    par1[128 + tid] = b0[tid] - mean * a;
  }
  __syncthreads();
  if (tid < 128) {
    par1[tid] = a1s[tid >> 3] * w0[tid];                 // w0p
    par1[144 + (tid & 15) * 8 + (tid >> 4)] = w1[tid];   // w1t
  }
}

// ---------------------------------------------------------------------------
// K3: stats2 — straight-line 4 px/thread (LICM-proof); z/z^2 partials.
__global__ __launch_bounds__(256) void k_stats2(
    const unsigned short* __restrict__ sB, const float* __restrict__ par1,
    float* __restrict__ part2) {
  __shared__ float w0ps[128], c1vs[16], w1ts[128];
  __shared__ float red[64];
  const int tid = threadIdx.x;
  if (tid < 128) {
    w0ps[tid] = par1[tid];
    w1ts[tid] = par1[144 + tid];
  }
  if (tid >= 128 && tid < 144) c1vs[tid - 128] = par1[tid];
  __syncthreads();

  const uint4* src = (const uint4*)sB + (size_t)blockIdx.x * 1024 + tid;
  float s0[8], s1[8], s2[8], s3[8];
  unpack8(src[0], s0);
  unpack8(src[256], s1);
  unpack8(src[512], s2);
  unpack8(src[768], s3);

  float z0[8], z1[8], z2[8], z3[8];
#pragma unroll
  for (int o = 0; o < 8; ++o) { z0[o] = 0.f; z1[o] = 0.f; z2[o] = 0.f; z3[o] = 0.f; }
#pragma unroll
  for (int c = 0; c < 16; ++c) {
    const float4 wa = *(const float4*)(w0ps + c * 8);
    const float4 wb = *(const float4*)(w0ps + c * 8 + 4);
    const float cc = c1vs[c];
    const float4 ta = *(const float4*)(w1ts + c * 8);
    const float4 tb = *(const float4*)(w1ts + c * 8 + 4);
    const float xa = fmaxf(dot8(s0, wa, wb) + cc, 0.f);
    const float xb = fmaxf(dot8(s1, wa, wb) + cc, 0.f);
    const float xc = fmaxf(dot8(s2, wa, wb) + cc, 0.f);
    const float xd = fmaxf(dot8(s3, wa, wb) + cc, 0.f);
    z0[0] += ta.x * xa; z0[1] += ta.y * xa; z0[2] += ta.z * xa; z0[3] += ta.w * xa;
    z0[4] += tb.x * xa; z0[5] += tb.y * xa; z0[6] += tb.z * xa; z0[7] += tb.w * xa;
    z1[0] += ta.x * xb; z1[1] += ta.y * xb; z1[2] += ta.z * xb; z1[3] += ta.w * xb;
    z1[4] += tb.x * xb; z1[5] += tb.y * xb; z1[6] += tb.z * xb; z1[7] += tb.w * xb;
    z2[0] += ta.x * xc; z2[1] += ta.y * xc; z2[2] += ta.z * xc; z2[3] += ta.w * xc;
    z2[4] += tb.x * xc; z2[5] += tb.y * xc; z2[6] += tb.z * xc; z2[7] += tb.w * xc;
    z3[0] += ta.x * xd; z3[1] += ta.y * xd; z3[2] += ta.z * xd; z3[3] += ta.w * xd;
    z3[4] += tb.x * xd; z3[5] += tb.y * xd; z3[6] += tb.z * xd; z3[7] += tb.w * xd;
  }

  const int wid = tid >> 6;
#pragma unroll
  for (int o = 0; o < 8; ++o) {
    float v = (z0[o] + z1[o]) + (z2[o] + z3[o]);
    float v2 = (z0[o] * z0[o] + z1[o] * z1[o]) + (z2[o] * z2[o] + z3[o] * z3[o]);
#pragma unroll
    for (int off = 32; off; off >>= 1) {
      v += __shfl_xor(v, off);
      v2 += __shfl_xor(v2, off);
    }
    if ((tid & 63) == 0) {
      red[wid * 16 + o] = v;
      red[wid * 16 + 8 + o] = v2;
    }
  }
  __syncthreads();
  if (tid < 16) {
    part2[blockIdx.x * 16 + tid] =
        red[tid] + red[16 + tid] + red[32 + tid] + red[48 + tid];
  }
}

// ---------------------------------------------------------------------------
// K3b: reduce2 (1 block) — part2 (1440 x 16) -> bn2.  ILP: 4 float4 cols x
// 64 chunks, 4 independent accumulators (chain ~6).
__global__ __launch_bounds__(256) void k_reduce2(
    const float* __restrict__ part2, const float* __restrict__ g1,
    const float* __restrict__ b1, const float* __restrict__ wsW,
    const float* __restrict__ bs, float* __restrict__ par2) {
  __shared__ float red[1024], totz[16];
  const int tid = threadIdx.x;
  {
    const int cq = tid & 3, chk = tid >> 2;  // 4 float4 cols x 64 chunks
    const float4* base = (const float4*)part2;  // 4 float4 per row
    float4 a0 = make_float4(0.f, 0.f, 0.f, 0.f), a1 = a0, a2 = a0, a3 = a0;
    int r = chk;
    while (r + 192 < NBT4) {
      addf4(a0, base[(size_t)(r)*4 + cq]);
      addf4(a1, base[(size_t)(r + 64) * 4 + cq]);
      addf4(a2, base[(size_t)(r + 128) * 4 + cq]);
      addf4(a3, base[(size_t)(r + 192) * 4 + cq]);
      r += 256;
    }
    for (; r < NBT4; r += 64) addf4(a0, base[(size_t)r * 4 + cq]);
    addf4(a0, a1); addf4(a2, a3); addf4(a0, a2);
    red[chk * 16 + cq * 4 + 0] = a0.x;
    red[chk * 16 + cq * 4 + 1] = a0.y;
    red[chk * 16 + cq * 4 + 2] = a0.z;
    red[chk * 16 + cq * 4 + 3] = a0.w;
  }
  __syncthreads();
  if (tid < 16) {
    float v = 0.f;
#pragma unroll
    for (int k = 0; k < 64; ++k) v += red[k * 16 + tid];
    totz[tid] = v;
  }
  __syncthreads();
  if (tid < 8) {
    const float invN = 1.f / (float)NPT;
    const float mean = totz[tid] * invN;
    const float var = totz[8 + tid] * invN - mean * mean;
    const float a = g1[tid] * rsqrtf(var + EPSV);
    par2[tid * 4 + 0] = a;
    par2[tid * 4 + 1] = b1[tid] - mean * a;
    par2[tid * 4 + 2] = wsW[tid];
    par2[tid * 4 + 3] = 0.f;
  }
  if (tid == 8) par2[32] = bs[0];
}

// ---------------------------------------------------------------------------
// K4: final — straight-line 4 px/thread, full MLP + sigmoid -> out.
// (Overwrites the partM region at the head of out.)
__global__ __launch_bounds__(256) void k_final(
    const unsigned short* __restrict__ sB, const float* __restrict__ par1,
    const float* __restrict__ par2, float* __restrict__ out) {
  __shared__ float w0ps[128], c1vs[16], w1ts[128], w2s[33];
  const int tid = threadIdx.x;
  if (tid < 128) {
    w0ps[tid] = par1[tid];
    w1ts[tid] = par1[144 + tid];
  }
  if (tid >= 128 && tid < 144) c1vs[tid - 128] = par1[tid];
  if (tid >= 160 && tid < 193) w2s[tid - 160] = par2[tid - 160];
  __syncthreads();

  const uint4* src = (const uint4*)sB + (size_t)blockIdx.x * 1024 + tid;
  float s0[8], s1[8], s2[8], s3[8];
  unpack8(src[0], s0);
  unpack8(src[256], s1);
  unpack8(src[512], s2);
  unpack8(src[768], s3);

  float z0[8], z1[8], z2[8], z3[8];
#pragma unroll
  for (int o = 0; o < 8; ++o) { z0[o] = 0.f; z1[o] = 0.f; z2[o] = 0.f; z3[o] = 0.f; }
#pragma unroll
  for (int c = 0; c < 16; ++c) {
    const float4 wa = *(const float4*)(w0ps + c * 8);
    const float4 wb = *(const float4*)(w0ps + c * 8 + 4);
    const float cc = c1vs[c];
    const float4 ta = *(const float4*)(w1ts + c * 8);
    const float4 tb = *(const float4*)(w1ts + c * 8 + 4);
    const float xa = fmaxf(dot8(s0, wa, wb) + cc, 0.f);
    const float xb = fmaxf(dot8(s1, wa, wb) + cc, 0.f);
    const float xc = fmaxf(dot8(s2, wa, wb) + cc, 0.f);
    const float xd = fmaxf(dot8(s3, wa, wb) + cc, 0.f);
    z0[0] += ta.x * xa; z0[1] += ta.y * xa; z0[2] += ta.z * xa; z0[3] += ta.w * xa;
    z0[4] += tb.x * xa; z0[5] += tb.y * xa; z0[6] += tb.z * xa; z0[7] += tb.w * xa;
    z1[0] += ta.x * xb; z1[1] += ta.y * xb; z1[2] += ta.z * xb; z1[3] += ta.w * xb;
    z1[4] += tb.x * xb; z1[5] += tb.y * xb; z1[6] += tb.z * xb; z1[7] += tb.w * xb;
    z2[0] += ta.x * xc; z2[1] += ta.y * xc; z2[2] += ta.z * xc; z2[3] += ta.w * xc;
    z2[4] += tb.x * xc; z2[5] += tb.y * xc; z2[6] += tb.z * xc; z2[7] += tb.w * xc;
    z3[0] += ta.x * xd; z3[1] += ta.y * xd; z3[2] += ta.z * xd; z3[3] += ta.w * xd;
    z3[4] += tb.x * xd; z3[5] += tb.y * xd; z3[6] += tb.z * xd; z3[7] += tb.w * xd;
  }

  const float bsr = w2s[32];
  float r0 = bsr, r1 = bsr, r2 = bsr, r3 = bsr;
#pragma unroll
  for (int o = 0; o < 8; ++o) {
    const float4 pr = *(const float4*)(w2s + o * 4);
    r0 += pr.z * fmaxf(fmaf(pr.x, z0[o], pr.y), 0.f);
    r1 += pr.z * fmaxf(fmaf(pr.x, z1[o], pr.y), 0.f);
    r2 += pr.z * fmaxf(fmaf(pr.x, z2[o], pr.y), 0.f);
    r3 += pr.z * fmaxf(fmaf(pr.x, z3[o], pr.y), 0.f);
  }
  float* op = out + (size_t)blockIdx.x * 1024 + tid;
  op[0]   = 1.f / (1.f + __expf(-r0));
  op[256] = 1.f / (1.f + __expf(-r1));
  op[512] = 1.f / (1.f + __expf(-r2));
  op[768] = 1.f / (1.f + __expf(-r3));
}

// ---------------------------------------------------------------------------
extern "C" void kernel_launch(void* const* d_in, const int* in_sizes, int n_in,
                              void* d_out, int out_size, void* d_ws,
                              size_t ws_size, hipStream_t stream) {
  const float* feat = (const float*)d_in[0];  // [2,64,256,320]
  const float* grid = (const float*)d_in[1];  // [2,2304,320,2]
  const float* w0 = (const float*)d_in[2];    // [16,8]
  const float* g0 = (const float*)d_in[3];
  const float* b0 = (const float*)d_in[4];
  const float* w1 = (const float*)d_in[5];    // [8,16]
  const float* g1 = (const float*)d_in[6];
  const float* b1 = (const float*)d_in[7];
  const float* wsW = (const float*)d_in[8];   // [1,8]
  const float* bs = (const float*)d_in[9];    // [1]
  float* out = (float*)d_out;

  float* wsf = (float*)d_ws;
  unsigned short* featB = (unsigned short*)(wsf + OFF_FEATB);
  unsigned short* sB    = (unsigned short*)(wsf + OFF_SB);
  float* part2 = wsf + OFF_P2;   // overlays featB (dead after k_sample)
  float* par1  = wsf + OFF_PAR1;
  float* par2  = wsf + OFF_PAR2;
  float* partM = out;            // 5120*72 floats; k_final overwrites

  k_transpose<<<Bc * (HWc / 64), 256, 0, stream>>>(feat, featB);
  k_sample<<<NBLK_S, 256, 0, stream>>>(grid, featB, sB, partM);
  k_reduce1<<<1, 256, 0, stream>>>(partM, w0, w1, g0, b0, par1);
  k_stats2<<<NBT4, 256, 0, stream>>>(sB, par1, part2);
  k_reduce2<<<1, 256, 0, stream>>>(part2, g1, b1, wsW, bs, par2);
  k_final<<<NBT4, 256, 0, stream>>>(sB, par1, par2, out);
}

// Round 10
// 226.280 us; speedup vs baseline: 2.7575x; 1.2084x over previous
//
#include <hip/hip_runtime.h>
#include <math.h>

// FeatureWeightNet: grid_sample(bilinear,border) -> group correlation (G=8) ->
// MLP(8->16->8->1) with per-batch BN stats -> sigmoid.
// R17 = R16 with the partM reduction PARALLELIZED (R16's 1-block reduce1
// streamed 1.47MB alone ~= 50-65us, hidden under the top-5 cutoff):
//  - k_sample writes partM COLUMN-major (72 cols x 5120 rows) -> scatter cost
//    hidden in the big kernel; reduce1a = 72 blocks each summing 5120
//    CONTIGUOUS floats (5 coalesced float4/thread) -> ~4us total.
//  - bn1 params computed inline in stats2/final prologues from the 72 totals
//    (L2-hot; 16-thread quadratic form) -> no reduce1b dispatch.
//  - reduce2 (92KB, ILP) and all main loops byte-identical to R16.
// Laws so far: no loops around LDS-weight reads (LICM->spill, R8-R10);
// no per-block device fences (R13); 1-block reduces only for <~100KB (R15/16).
// 6 dispatches.

constexpr int   Bc  = 2;
constexpr int   Cc  = 64;
constexpr int   Hc  = 256;
constexpr int   Wc  = 320;
constexpr int   NBc = 9;
constexpr int   HWc = Hc * Wc;            // 81920
constexpr int   NPIX = Bc * HWc;          // 163840
constexpr int   NPT  = Bc * NBc * HWc;    // 1474560 (= out_size)
constexpr float EPSV = 1e-5f;

constexpr int NBLK_S = NPIX / 32;         // 5120 sample blocks
constexpr int NBT4   = NPT / 1024;        // 1440 tail blocks (4 px/thread)

// workspace layout in float units.  featB (21 MB) + sB (23.6 MB).
constexpr size_t OFF_FEATB = 0;                               // NHWC bf16: NPIX*64 ushort
constexpr size_t OFF_SB    = OFF_FEATB + (size_t)NPIX * 32;   // s bf16: NPT*8 ushort
// scratch overlays featB (dead after k_sample):
constexpr size_t OFF_P2    = 0;                                // NBT4*16 floats
constexpr size_t OFF_PAR2  = OFF_P2 + (size_t)NBT4 * 16;       // 33 floats
constexpr size_t OFF_TOT   = OFF_PAR2 + 64;                    // 72 floats

__device__ __forceinline__ unsigned short f2bf_rne(float v) {
  unsigned int u = __float_as_uint(v);
  unsigned int r = (u + 0x7fffu + ((u >> 16) & 1u)) >> 16;
  return (unsigned short)r;
}
__device__ __forceinline__ void unpack8(uint4 u, float f[8]) {
  f[0] = __uint_as_float(u.x << 16);
  f[1] = __uint_as_float(u.x & 0xffff0000u);
  f[2] = __uint_as_float(u.y << 16);
  f[3] = __uint_as_float(u.y & 0xffff0000u);
  f[4] = __uint_as_float(u.z << 16);
  f[5] = __uint_as_float(u.z & 0xffff0000u);
  f[6] = __uint_as_float(u.w << 16);
  f[7] = __uint_as_float(u.w & 0xffff0000u);
}
__device__ __forceinline__ float dot8(const float s[8], float4 wa, float4 wb) {
  return s[0] * wa.x + s[1] * wa.y + s[2] * wa.z + s[3] * wa.w +
         s[4] * wb.x + s[5] * wb.y + s[6] * wb.z + s[7] * wb.w;
}
__device__ __forceinline__ void addf4(float4& a, const float4 v) {
  a.x += v.x; a.y += v.y; a.z += v.z; a.w += v.w;
}

// ---------------------------------------------------------------------------
// K0: NCHW fp32 -> NHWC bf16 transpose.
__global__ __launch_bounds__(256) void k_transpose(
    const float* __restrict__ feat, unsigned short* __restrict__ featB) {
  __shared__ float lds[64][65];
  const int tid  = threadIdx.x;
  const int b    = blockIdx.x / (HWc / 64);
  const int tile = blockIdx.x % (HWc / 64);
  const int hw0  = tile * 64;
  const int p    = tid & 63;
  const int ty   = tid >> 6;  // 0..3

  const float* src = feat + (size_t)b * Cc * HWc + hw0 + p;
#pragma unroll
  for (int c0 = 0; c0 < 64; c0 += 4) {
    lds[c0 + ty][p] = src[(size_t)(c0 + ty) * HWc];
  }
  __syncthreads();
  const int ch = tid & 63;
  unsigned short* dst = featB + ((size_t)b * HWc + hw0) * 64 + ch;
#pragma unroll
  for (int p0 = 0; p0 < 64; p0 += 4) {
    dst[(size_t)(p0 + ty) * 64] = f2bf_rne(lds[ch][p0 + ty]);
  }
}

// ---------------------------------------------------------------------------
// K1: grid sample + group correlation + FUSED s-moment partials (col-major).
__global__ __launch_bounds__(256) void k_sample(
    const float* __restrict__ grid, const unsigned short* __restrict__ featB,
    unsigned short* __restrict__ sOut, float* __restrict__ partM) {
  const int tid = threadIdx.x;
  const int cid = blockIdx.x * 32 + (tid >> 3);  // pixel id in [0, NPIX)
  const int j   = tid & 7;                       // group
  const int b   = cid / HWc;
  const int hw  = cid - b * HWc;
  const int h   = hw / Wc;
  const int w   = hw - h * Wc;

  const uint4* fbAll = (const uint4*)featB;
  const uint4 ur = fbAll[(size_t)cid * 8 + j];
  float r[8];
  unpack8(ur, r);

  const uint4* fb = fbAll + (size_t)b * HWc * 8;

  float macc[8];
#pragma unroll
  for (int m = 0; m < 8; ++m) macc[m] = 0.f;
  float msum = 0.f;

#pragma unroll 3
  for (int n = 0; n < NBc; ++n) {
    const size_t gi = ((((size_t)b * NBc + n) * Hc + h) * Wc + w) * 2;
    const float2 g2 = *(const float2*)(grid + gi);
    float ix = ((g2.x + 1.f) * (float)Wc - 1.f) * 0.5f;
    float iy = ((g2.y + 1.f) * (float)Hc - 1.f) * 0.5f;
    ix = fminf(fmaxf(ix, 0.f), (float)(Wc - 1));
    iy = fminf(fmaxf(iy, 0.f), (float)(Hc - 1));
    const float x0f = floorf(ix), y0f = floorf(iy);
    const float fx = ix - x0f, fy = iy - y0f;
    const int x0 = (int)x0f, y0 = (int)y0f;
    const int x1 = min(x0 + 1, Wc - 1), y1 = min(y0 + 1, Hc - 1);
    const float w00 = (1.f - fx) * (1.f - fy);
    const float w01 = fx * (1.f - fy);
    const float w10 = (1.f - fx) * fy;
    const float w11 = fx * fy;

    const uint4 u00 = fb[(size_t)(y0 * Wc + x0) * 8 + j];
    const uint4 u01 = fb[(size_t)(y0 * Wc + x1) * 8 + j];
    const uint4 u10 = fb[(size_t)(y1 * Wc + x0) * 8 + j];
    const uint4 u11 = fb[(size_t)(y1 * Wc + x1) * 8 + j];
    float a[8], c[8], d[8], e[8];
    unpack8(u00, a);
    unpack8(u01, c);
    unpack8(u10, d);
    unpack8(u11, e);

    float s = 0.f;
#pragma unroll
    for (int k = 0; k < 8; ++k) {
      s += (w00 * a[k] + w01 * c[k] + w10 * d[k] + w11 * e[k]) * r[k];
    }
    s *= 0.125f;  // mean over C/G = 8

    const size_t pt = ((size_t)b * NBc + n) * HWc + hw;
    sOut[pt * 8 + j] = f2bf_rne(s);

    // fused moments: lanes j..j^7 are the 8 groups of THIS pixel.
    macc[0] += s * s;
#pragma unroll
    for (int m = 1; m < 8; ++m) macc[m] += s * __shfl_xor(s, m);
    msum += s;
  }

  // cross-pixel reduce: lanes differing in bits 3..5 hold other pixels.
#pragma unroll
  for (int m = 0; m < 8; ++m) {
    macc[m] += __shfl_xor(macc[m], 8);
    macc[m] += __shfl_xor(macc[m], 16);
    macc[m] += __shfl_xor(macc[m], 32);
  }
  msum += __shfl_xor(msum, 8);
  msum += __shfl_xor(msum, 16);
  msum += __shfl_xor(msum, 32);

  __shared__ float mred[4][72];
  const int lane = tid & 63, wid = tid >> 6;
  if (lane < 8) {
#pragma unroll
    for (int m = 0; m < 8; ++m) mred[wid][lane * 9 + m] = macc[m];
    mred[wid][lane * 9 + 8] = msum;
  }
  __syncthreads();
  // COLUMN-MAJOR: partM[col][blk] so reduce1a reads contiguous columns.
  if (tid < 72) {
    partM[(size_t)tid * NBLK_S + blockIdx.x] =
        mred[0][tid] + mred[1][tid] + mred[2][tid] + mred[3][tid];
  }
}

// ---------------------------------------------------------------------------
// K2: reduce1a — 72 blocks; block c sums its contiguous 5120-float column.
// 5 coalesced float4 loads per thread (1280 f4 total), ILP, LDS fold.
__global__ __launch_bounds__(256) void k_reduce1a(
    const float* __restrict__ partM, float* __restrict__ tot) {
  const int tid = threadIdx.x;
  const float4* base = (const float4*)(partM + (size_t)blockIdx.x * NBLK_S);
  float4 a0 = base[tid];
  float4 a1 = base[tid + 256];
  float4 a2 = base[tid + 512];
  float4 a3 = base[tid + 768];
  float4 a4 = base[tid + 1024];
  addf4(a0, a1); addf4(a2, a3); addf4(a0, a2); addf4(a0, a4);
  float v = (a0.x + a0.y) + (a0.z + a0.w);
#pragma unroll
  for (int off = 32; off; off >>= 1) v += __shfl_xor(v, off);
  __shared__ float red[4];
  if ((tid & 63) == 0) red[tid >> 6] = v;
  __syncthreads();
  if (tid == 0) tot[blockIdx.x] = (red[0] + red[1]) + (red[2] + red[3]);
}

// ---------------------------------------------------------------------------
// shared prologue: tot[72] -> bn1 params -> folded LDS weights.
// M[j][k] = tot[j*9 + (j^k)]; S[j] = tot[j*9+8].
__device__ __forceinline__ void bn1_prologue(
    const float* __restrict__ tot, const float* __restrict__ w0,
    const float* __restrict__ w1, const float* __restrict__ g0,
    const float* __restrict__ b0, float* tots, float* a1sS, float* w0ps,
    float* c1vs, float* w1ts) {
  const int tid = threadIdx.x;
  if (tid < 72) tots[tid] = tot[tid];
  __syncthreads();
  if (tid < 16) {
    float wr[8];
    float mean = 0.f, ey2 = 0.f;
#pragma unroll
    for (int jj = 0; jj < 8; ++jj) {
      wr[jj] = w0[tid * 8 + jj];
      mean += wr[jj] * tots[jj * 9 + 8];
    }
#pragma unroll
    for (int jj = 0; jj < 8; ++jj) {
#pragma unroll
      for (int kk = 0; kk < 8; ++kk) {
        ey2 += wr[jj] * wr[kk] * tots[jj * 9 + (jj ^ kk)];
      }
    }
    const float invN = 1.f / (float)NPT;
    mean *= invN;
    ey2 *= invN;
    const float var = ey2 - mean * mean;
    const float a = g0[tid] * rsqrtf(var + EPSV);
    a1sS[tid] = a;
    c1vs[tid] = b0[tid] - mean * a;
  }
  __syncthreads();
  if (tid < 128) {
    w0ps[tid] = a1sS[tid >> 3] * w0[tid];            // a1-folded w0
    w1ts[(tid & 15) * 8 + (tid >> 4)] = w1[tid];     // w1 transposed [c][o]
  }
  __syncthreads();
}

// ---------------------------------------------------------------------------
// K3: stats2 — prologue computes bn1 inline; straight-line 4 px/thread
// (LICM-proof); z/z^2 partials.
__global__ __launch_bounds__(256) void k_stats2(
    const unsigned short* __restrict__ sB, const float* __restrict__ tot,
    const float* __restrict__ w0, const float* __restrict__ w1,
    const float* __restrict__ g0, const float* __restrict__ b0,
    float* __restrict__ part2) {
  __shared__ float tots[72], a1sS[16], w0ps[128], c1vs[16], w1ts[128];
  __shared__ float red[64];
  const int tid = threadIdx.x;
  bn1_prologue(tot, w0, w1, g0, b0, tots, a1sS, w0ps, c1vs, w1ts);

  const uint4* src = (const uint4*)sB + (size_t)blockIdx.x * 1024 + tid;
  float s0[8], s1[8], s2[8], s3[8];
  unpack8(src[0], s0);
  unpack8(src[256], s1);
  unpack8(src[512], s2);
  unpack8(src[768], s3);

  float z0[8], z1[8], z2[8], z3[8];
#pragma unroll
  for (int o = 0; o < 8; ++o) { z0[o] = 0.f; z1[o] = 0.f; z2[o] = 0.f; z3[o] = 0.f; }
#pragma unroll
  for (int c = 0; c < 16; ++c) {
    const float4 wa = *(const float4*)(w0ps + c * 8);
    const float4 wb = *(const float4*)(w0ps + c * 8 + 4);
    const float cc = c1vs[c];
    const float4 ta = *(const float4*)(w1ts + c * 8);
    const float4 tb = *(const float4*)(w1ts + c * 8 + 4);
    const float xa = fmaxf(dot8(s0, wa, wb) + cc, 0.f);
    const float xb = fmaxf(dot8(s1, wa, wb) + cc, 0.f);
    const float xc = fmaxf(dot8(s2, wa, wb) + cc, 0.f);
    const float xd = fmaxf(dot8(s3, wa, wb) + cc, 0.f);
    z0[0] += ta.x * xa; z0[1] += ta.y * xa; z0[2] += ta.z * xa; z0[3] += ta.w * xa;
    z0[4] += tb.x * xa; z0[5] += tb.y * xa; z0[6] += tb.z * xa; z0[7] += tb.w * xa;
    z1[0] += ta.x * xb; z1[1] += ta.y * xb; z1[2] += ta.z * xb; z1[3] += ta.w * xb;
    z1[4] += tb.x * xb; z1[5] += tb.y * xb; z1[6] += tb.z * xb; z1[7] += tb.w * xb;
    z2[0] += ta.x * xc; z2[1] += ta.y * xc; z2[2] += ta.z * xc; z2[3] += ta.w * xc;
    z2[4] += tb.x * xc; z2[5] += tb.y * xc; z2[6] += tb.z * xc; z2[7] += tb.w * xc;
    z3[0] += ta.x * xd; z3[1] += ta.y * xd; z3[2] += ta.z * xd; z3[3] += ta.w * xd;
    z3[4] += tb.x * xd; z3[5] += tb.y * xd; z3[6] += tb.z * xd; z3[7] += tb.w * xd;
  }

  const int wid = tid >> 6;
#pragma unroll
  for (int o = 0; o < 8; ++o) {
    float v = (z0[o] + z1[o]) + (z2[o] + z3[o]);
    float v2 = (z0[o] * z0[o] + z1[o] * z1[o]) + (z2[o] * z2[o] + z3[o] * z3[o]);
#pragma unroll
    for (int off = 32; off; off >>= 1) {
      v += __shfl_xor(v, off);
      v2 += __shfl_xor(v2, off);
    }
    if ((tid & 63) == 0) {
      red[wid * 16 + o] = v;
      red[wid * 16 + 8 + o] = v2;
    }
  }
  __syncthreads();
  if (tid < 16) {
    part2[blockIdx.x * 16 + tid] =
        red[tid] + red[16 + tid] + red[32 + tid] + red[48 + tid];
  }
}

// ---------------------------------------------------------------------------
// K3b: reduce2 (1 block, 92KB — small enough per R15/16 law) — part2 -> bn2.
// ILP: 4 float4 cols x 64 chunks, 4 independent accumulators.
__global__ __launch_bounds__(256) void k_reduce2(
    const float* __restrict__ part2, const float* __restrict__ g1,
    const float* __restrict__ b1, const float* __restrict__ wsW,
    const float* __restrict__ bs, float* __restrict__ par2) {
  __shared__ float red[1024], totz[16];
  const int tid = threadIdx.x;
  {
    const int cq = tid & 3, chk = tid >> 2;  // 4 float4 cols x 64 chunks
    const float4* base = (const float4*)part2;  // 4 float4 per row
    float4 a0 = make_float4(0.f, 0.f, 0.f, 0.f), a1 = a0, a2 = a0, a3 = a0;
    int r = chk;
    while (r + 192 < NBT4) {
      addf4(a0, base[(size_t)(r)*4 + cq]);
      addf4(a1, base[(size_t)(r + 64) * 4 + cq]);
      addf4(a2, base[(size_t)(r + 128) * 4 + cq]);
      addf4(a3, base[(size_t)(r + 192) * 4 + cq]);
      r += 256;
    }
    for (; r < NBT4; r += 64) addf4(a0, base[(size_t)r * 4 + cq]);
    addf4(a0, a1); addf4(a2, a3); addf4(a0, a2);
    red[chk * 16 + cq * 4 + 0] = a0.x;
    red[chk * 16 + cq * 4 + 1] = a0.y;
    red[chk * 16 + cq * 4 + 2] = a0.z;
    red[chk * 16 + cq * 4 + 3] = a0.w;
  }
  __syncthreads();
  if (tid < 16) {
    float v = 0.f;
#pragma unroll
    for (int k = 0; k < 64; ++k) v += red[k * 16 + tid];
    totz[tid] = v;
  }
  __syncthreads();
  if (tid < 8) {
    const float invN = 1.f / (float)NPT;
    const float mean = totz[tid] * invN;
    const float var = totz[8 + tid] * invN - mean * mean;
    const float a = g1[tid] * rsqrtf(var + EPSV);
    par2[tid * 4 + 0] = a;
    par2[tid * 4 + 1] = b1[tid] - mean * a;
    par2[tid * 4 + 2] = wsW[tid];
    par2[tid * 4 + 3] = 0.f;
  }
  if (tid == 8) par2[32] = bs[0];
}

// ---------------------------------------------------------------------------
// K4: final — prologue: bn1 inline + bn2 from par2; straight-line 4 px/thread;
// full MLP + sigmoid -> out (overwrites the partM region).
__global__ __launch_bounds__(256) void k_final(
    const unsigned short* __restrict__ sB, const float* __restrict__ tot,
    const float* __restrict__ w0, const float* __restrict__ w1,
    const float* __restrict__ g0, const float* __restrict__ b0,
    const float* __restrict__ par2, float* __restrict__ out) {
  __shared__ float tots[72], a1sS[16], w0ps[128], c1vs[16], w1ts[128];
  __shared__ float w2s[33];
  const int tid = threadIdx.x;
  if (tid >= 160 && tid < 193) w2s[tid - 160] = par2[tid - 160];
  bn1_prologue(tot, w0, w1, g0, b0, tots, a1sS, w0ps, c1vs, w1ts);

  const uint4* src = (const uint4*)sB + (size_t)blockIdx.x * 1024 + tid;
  float s0[8], s1[8], s2[8], s3[8];
  unpack8(src[0], s0);
  unpack8(src[256], s1);
  unpack8(src[512], s2);
  unpack8(src[768], s3);

  float z0[8], z1[8], z2[8], z3[8];
#pragma unroll
  for (int o = 0; o < 8; ++o) { z0[o] = 0.f; z1[o] = 0.f; z2[o] = 0.f; z3[o] = 0.f; }
#pragma unroll
  for (int c = 0; c < 16; ++c) {
    const float4 wa = *(const float4*)(w0ps + c * 8);
    const float4 wb = *(const float4*)(w0ps + c * 8 + 4);
    const float cc = c1vs[c];
    const float4 ta = *(const float4*)(w1ts + c * 8);
    const float4 tb = *(const float4*)(w1ts + c * 8 + 4);
    const float xa = fmaxf(dot8(s0, wa, wb) + cc, 0.f);
    const float xb = fmaxf(dot8(s1, wa, wb) + cc, 0.f);
    const float xc = fmaxf(dot8(s2, wa, wb) + cc, 0.f);
    const float xd = fmaxf(dot8(s3, wa, wb) + cc, 0.f);
    z0[0] += ta.x * xa; z0[1] += ta.y * xa; z0[2] += ta.z * xa; z0[3] += ta.w * xa;
    z0[4] += tb.x * xa; z0[5] += tb.y * xa; z0[6] += tb.z * xa; z0[7] += tb.w * xa;
    z1[0] += ta.x * xb; z1[1] += ta.y * xb; z1[2] += ta.z * xb; z1[3] += ta.w * xb;
    z1[4] += tb.x * xb; z1[5] += tb.y * xb; z1[6] += tb.z * xb; z1[7] += tb.w * xb;
    z2[0] += ta.x * xc; z2[1] += ta.y * xc; z2[2] += ta.z * xc; z2[3] += ta.w * xc;
    z2[4] += tb.x * xc; z2[5] += tb.y * xc; z2[6] += tb.z * xc; z2[7] += tb.w * xc;
    z3[0] += ta.x * xd; z3[1] += ta.y * xd; z3[2] += ta.z * xd; z3[3] += ta.w * xd;
    z3[4] += tb.x * xd; z3[5] += tb.y * xd; z3[6] += tb.z * xd; z3[7] += tb.w * xd;
  }

  const float bsr = w2s[32];
  float r0 = bsr, r1 = bsr, r2 = bsr, r3 = bsr;
#pragma unroll
  for (int o = 0; o < 8; ++o) {
    const float4 pr = *(const float4*)(w2s + o * 4);
    r0 += pr.z * fmaxf(fmaf(pr.x, z0[o], pr.y), 0.f);
    r1 += pr.z * fmaxf(fmaf(pr.x, z1[o], pr.y), 0.f);
    r2 += pr.z * fmaxf(fmaf(pr.x, z2[o], pr.y), 0.f);
    r3 += pr.z * fmaxf(fmaf(pr.x, z3[o], pr.y), 0.f);
  }
  float* op = out + (size_t)blockIdx.x * 1024 + tid;
  op[0]   = 1.f / (1.f + __expf(-r0));
  op[256] = 1.f / (1.f + __expf(-r1));
  op[512] = 1.f / (1.f + __expf(-r2));
  op[768] = 1.f / (1.f + __expf(-r3));
}

// ---------------------------------------------------------------------------
extern "C" void kernel_launch(void* const* d_in, const int* in_sizes, int n_in,
                              void* d_out, int out_size, void* d_ws,
                              size_t ws_size, hipStream_t stream) {
  const float* feat = (const float*)d_in[0];  // [2,64,256,320]
  const float* grid = (const float*)d_in[1];  // [2,2304,320,2]
  const float* w0 = (const float*)d_in[2];    // [16,8]
  const float* g0 = (const float*)d_in[3];
  const float* b0 = (const float*)d_in[4];
  const float* w1 = (const float*)d_in[5];    // [8,16]
  const float* g1 = (const float*)d_in[6];
  const float* b1 = (const float*)d_in[7];
  const float* wsW = (const float*)d_in[8];   // [1,8]
  const float* bs = (const float*)d_in[9];    // [1]
  float* out = (float*)d_out;

  float* wsf = (float*)d_ws;
  unsigned short* featB = (unsigned short*)(wsf + OFF_FEATB);
  unsigned short* sB    = (unsigned short*)(wsf + OFF_SB);
  float* part2 = wsf + OFF_P2;   // overlays featB (dead after k_sample)
  float* par2  = wsf + OFF_PAR2;
  float* tot   = wsf + OFF_TOT;
  float* partM = out;            // 72*5120 floats (col-major); final overwrites

  k_transpose<<<Bc * (HWc / 64), 256, 0, stream>>>(feat, featB);
  k_sample<<<NBLK_S, 256, 0, stream>>>(grid, featB, sB, partM);
  k_reduce1a<<<72, 256, 0, stream>>>(partM, tot);
  k_stats2<<<NBT4, 256, 0, stream>>>(sB, tot, w0, w1, g0, b0, part2);
  k_reduce2<<<1, 256, 0, stream>>>(part2, g1, b1, wsW, bs, par2);
  k_final<<<NBT4, 256, 0, stream>>>(sB, tot, w0, w1, g0, b0, par2, out);
}